// Round 4
// baseline (5634.584 us; speedup 1.0000x reference)
//
#include <hip/hip_runtime.h>

// GRU, B=64, N=1024, T=512.
// Phase 1 (parallel): transpose x, weights -> bf16 [n][k], precompute
//   P2[t][s][j][b] = (x_t @ {W1z,W1r,W2} + bias) in bf16.
// Phase 2: ONE persistent kernel (cooperative launch for co-residency),
//   256 blocks x 256 thr = 4 INDEPENDENT 64-block scans (one per 16-batch
//   group mq). No grid barrier: decentralized ready-flags (f[bid]=step) +
//   4-deep h ring buffer + lagged consumed-flags (cons[bid]) for reuse.
//   All cross-block h traffic via relaxed agent-scope (sc1/LLC) atomics.

#define BATCH 64
#define NN 1024
#define TSTEPS 512
#define HB_ELEMS ((size_t)BATCH * NN)          // 65536 shorts per ring slot

typedef __attribute__((ext_vector_type(8))) short short8;
typedef __attribute__((ext_vector_type(8))) unsigned short u16x8;
typedef __attribute__((ext_vector_type(4))) unsigned short u16x4;
typedef __attribute__((ext_vector_type(4))) float f32x4;

#define MFMA16(a, b, c) __builtin_amdgcn_mfma_f32_16x16x32_bf16((a), (b), (c), 0, 0, 0)

__device__ __forceinline__ unsigned short f2bf(float x) {
  union { float f; unsigned u; } v; v.f = x;
  unsigned u = v.u + 0x7FFFu + ((v.u >> 16) & 1u);   // round-to-nearest-even
  return (unsigned short)(u >> 16);
}
__device__ __forceinline__ float bf2f(unsigned short h) {
  union { unsigned u; float f; } v; v.u = ((unsigned)h) << 16; return v.f;
}

// ---- transpose flow_x [64][1024][512] fp32 -> xT [(t*64+b)][k] bf16 ----
__global__ void trans_x(const float* __restrict__ fx, unsigned short* __restrict__ xT) {
  int bid = blockIdx.x;
  int b   = bid >> 7;
  int rem = bid & 127;
  int kt  = rem >> 3;
  int tt  = rem & 7;
  __shared__ float tl[64][65];
  int tx = threadIdx.x & 63;
  int ty = threadIdx.x >> 6;
  const float* src = fx + ((size_t)(b * NN + kt * 64)) * TSTEPS + tt * 64;
#pragma unroll
  for (int i = 0; i < 16; i++) {
    int kr = i * 4 + ty;
    tl[kr][tx] = src[(size_t)kr * TSTEPS + tx];
  }
  __syncthreads();
#pragma unroll
  for (int i = 0; i < 16; i++) {
    int tr = i * 4 + ty;
    xT[((size_t)((tt * 64 + tr) * 64 + b)) * NN + kt * 64 + tx] = f2bf(tl[tx][tr]);
  }
}

// ---- weights fp32 -> wt bf16 [3*1024 rows n=(s,j)][1024 k] ----
__global__ void prep_w(const float* __restrict__ W1, const float* __restrict__ W2,
                       unsigned short* __restrict__ wt) {
  int bid = blockIdx.x;
  int s    = bid >> 8;
  int tile = bid & 255;
  int kt = tile >> 4, jt = tile & 15;
  const float* src = (s < 2) ? W1 : W2;
  int ld = (s < 2) ? 2048 : 1024;
  int co = (s == 1) ? 1024 : 0;
  __shared__ float tl[64][65];
  int tx = threadIdx.x & 63, ty = threadIdx.x >> 6;
#pragma unroll
  for (int i = 0; i < 16; i++) {
    int kr = i * 4 + ty;
    tl[kr][tx] = src[(size_t)(kt * 64 + kr) * ld + co + jt * 64 + tx];
  }
  __syncthreads();
#pragma unroll
  for (int i = 0; i < 16; i++) {
    int jr = i * 4 + ty;
    wt[((size_t)(s * NN + jt * 64 + jr)) * NN + kt * 64 + tx] = f2bf(tl[tx][jr]);
  }
}

// ---- P2[t][s][j][b] = x @ [W1 | W2] + bias, bf16 ----
__global__ __launch_bounds__(256) void precompute(
    const unsigned short* __restrict__ xT, const unsigned short* __restrict__ wt,
    const float* __restrict__ b1, const float* __restrict__ b2,
    unsigned short* __restrict__ P2) {
  int m0 = (blockIdx.x / 24) * 128;
  int n0 = (blockIdx.x % 24) * 128;
  __shared__ unsigned short As[128 * 40];
  __shared__ unsigned short Bs[128 * 40];
  int tid = threadIdx.x;
  int wave = tid >> 6, lane = tid & 63, q = lane >> 4, li = lane & 15;
  int wm = wave >> 1, wn = wave & 1;
  f32x4 acc[4][4];
#pragma unroll
  for (int a = 0; a < 4; a++)
#pragma unroll
    for (int b = 0; b < 4; b++) acc[a][b] = (f32x4)(0.f);

  for (int kk = 0; kk < 32; ++kk) {
    int K0 = kk * 32;
#pragma unroll
    for (int e = 0; e < 2; e++) {
      int c = tid * 2 + e;
      int row = c >> 2, part = c & 3;
      *(u16x8*)&As[row * 40 + part * 8] =
          *(const u16x8*)&xT[(size_t)(m0 + row) * NN + K0 + part * 8];
      *(u16x8*)&Bs[row * 40 + part * 8] =
          *(const u16x8*)&wt[(size_t)(n0 + row) * NN + K0 + part * 8];
    }
    __syncthreads();
    short8 af[4], bfr[4];
#pragma unroll
    for (int mt = 0; mt < 4; mt++)
      af[mt] = *(const short8*)&As[(wm * 64 + mt * 16 + li) * 40 + q * 8];
#pragma unroll
    for (int nt = 0; nt < 4; nt++)
      bfr[nt] = *(const short8*)&Bs[(wn * 64 + nt * 16 + li) * 40 + q * 8];
#pragma unroll
    for (int mt = 0; mt < 4; mt++)
#pragma unroll
      for (int nt = 0; nt < 4; nt++)
        acc[mt][nt] = MFMA16(af[mt], bfr[nt], acc[mt][nt]);
    __syncthreads();
  }
#pragma unroll
  for (int mt = 0; mt < 4; mt++) {
    int m = m0 + wm * 64 + mt * 16 + q * 4;
    int t = m >> 6, b = m & 63;
#pragma unroll
    for (int nt = 0; nt < 4; nt++) {
      int n = n0 + wn * 64 + nt * 16 + li;
      float bias = (n < 2048) ? b1[n] : b2[n - 2048];
      int s = n >> 10, j = n & 1023;
      f32x4 a = acc[mt][nt];
      u16x4 pk;
      pk.x = f2bf(a.x + bias); pk.y = f2bf(a.y + bias);
      pk.z = f2bf(a.z + bias); pk.w = f2bf(a.w + bias);
      *(u16x4*)&P2[(((size_t)t * 3 + s) * NN + j) * 64 + b] = pk;
    }
  }
}

#define AL(p)    __hip_atomic_load((p),  __ATOMIC_RELAXED, __HIP_MEMORY_SCOPE_AGENT)
#define AS(p, v) __hip_atomic_store((p), (v), __ATOMIC_RELAXED, __HIP_MEMORY_SCOPE_AGENT)

// ---- persistent scan, decentralized flag sync ----
// hb: ring of 4 slots, each [64 b][1024 j] bf16. Slot (t&3) holds h_t.
// f[bid]   = s  => block bid has published h_s (and it is LLC-visible).
// cons[bid]= s  => block bid has retired all its A-loads of h_{s-1}.
__global__ __launch_bounds__(256, 1) void gru_scan(
    unsigned short* __restrict__ hb, const unsigned short* __restrict__ wt,
    const unsigned short* __restrict__ P2,
    const float* __restrict__ b1, const float* __restrict__ b2,
    float* __restrict__ out, unsigned* __restrict__ f, unsigned* __restrict__ cons) {
  int bid = blockIdx.x;
  int jt = bid & 63, mq = bid >> 6;
  int j0 = jt * 16, m0 = mq * 16;
  int grp = mq * 64;
  int tid = threadIdx.x, wave = tid >> 6, lane = tid & 63, q = lane >> 4, li = lane & 15;
  int kb = wave * 256;   // this wave's K-quarter

  // gate-weight fragments (compiler chooses regs vs per-iter L1/L2 reload)
  const short8* Bz = (const short8*)&wt[((size_t)(0 * NN + j0 + li)) * NN + kb + q * 8];
  const short8* Br = (const short8*)&wt[((size_t)(1 * NN + j0 + li)) * NN + kb + q * 8];
  const short8* Bv = (const short8*)&wt[((size_t)(2 * NN + j0 + li)) * NN + kb + q * 8];
  short8 wz[8], wr[8], wv[8];
#pragma unroll
  for (int r = 0; r < 8; r++) {
    wz[r] = Bz[r * 4];
    wr[r] = Br[r * 4];
    wv[r] = Bv[r * 4];
  }

  int j = j0 + li;
  int bbase = m0 + q * 4;
  float b1z = b1[j], b1r = b1[NN + j], b2v = b2[j];
  const unsigned short* pz = &P2[((size_t)0 * NN + j) * 64 + bbase];
  const unsigned short* pr = &P2[((size_t)1 * NN + j) * 64 + bbase];
  const unsigned short* pv = &P2[((size_t)2 * NN + j) * 64 + bbase];
  const size_t pstride = (size_t)3 * NN * 64;

  // A-fragment offset in u64 units within a ring slot
  const size_t aoff = (size_t)(m0 + li) * 256 + wave * 64 + q * 2;

  f32x4 hc = (f32x4)(0.f);   // wave0: fp32 h tile, resident all 512 steps
  __shared__ f32x4 red[9][64];

  for (int t = 0; t < TSTEPS; t++) {
    u16x4 pz4, pr4, pv4;
    if (wave == 0) {   // HBM P2 stream — issue first, consumed after reduce
      pz4 = *(const u16x4*)pz;
      pr4 = *(const u16x4*)pr;
      pv4 = *(const u16x4*)pv;
    }
    // wait until every writer in this group has published h_t
    if (t > 0) {
      unsigned v;
      do { v = AL(&f[grp + lane]); } while (__any((int)v < t));
    }
    // coherent A-loads from ring slot t&3 (16x dwordx2 per lane)
    const unsigned long long* hin =
        (const unsigned long long*)(hb + ((size_t)(t & 3)) * HB_ELEMS);
    union { unsigned long long u[2]; short8 s; } fa[8];
#pragma unroll
    for (int r = 0; r < 8; r++) {
      fa[r].u[0] = AL(hin + aoff + r * 8);
      fa[r].u[1] = AL(hin + aoff + r * 8 + 1);
    }
    f32x4 az = (f32x4)(0.f), ar = (f32x4)(0.f), av = (f32x4)(0.f);
#pragma unroll
    for (int r = 0; r < 8; r++) {
      az = MFMA16(fa[r].s, wz[r], az);
      ar = MFMA16(fa[r].s, wr[r], ar);
      av = MFMA16(fa[r].s, wv[r], av);
    }
    if (wave > 0) {
      red[(wave - 1) * 3 + 0][lane] = az;
      red[(wave - 1) * 3 + 1][lane] = ar;
      red[(wave - 1) * 3 + 2][lane] = av;
    }
    __syncthreads();   // also implies: all 4 waves' A-loads are retired
    if (tid == 0) AS(&cons[bid], (unsigned)(t + 1));
    if (wave == 0) {
#pragma unroll
      for (int w = 0; w < 3; w++) {
        az += red[w * 3 + 0][lane];
        ar += red[w * 3 + 1][lane];
        av += red[w * 3 + 2][lane];
      }
#pragma unroll
      for (int reg = 0; reg < 4; reg++) {
        float z = 1.f / (1.f + __expf(-(az[reg] + bf2f(pz4[reg]) + b1z)));
        float r = 1.f / (1.f + __expf(-(ar[reg] + bf2f(pr4[reg]) + b1r)));
        float x = bf2f(pv4[reg]) + r * (av[reg] + b2v);
        float e = __expf(-2.f * fabsf(x));        // overflow-safe tanh
        float th = (1.f - e) / (1.f + e);
        float hh = (x >= 0.f) ? th : -th;
        hc[reg] = z * hc[reg] + (1.f - z) * hh;
      }
      // ring-reuse clearance: slot (t+1)&3 held h_{t-3}, consumed at step t-3
      // (=> cons >= t-2). Steady-state: passes on first poll.
      if (t >= 3) {
        unsigned c;
        do { c = AL(&cons[grp + lane]); } while (__any((int)c < t - 2));
      }
      // publish h_{t+1} into slot (t+1)&3: hb[b][j], adjacent-j pairs packed
      unsigned* hout = (unsigned*)(hb + ((size_t)((t + 1) & 3)) * HB_ELEMS);
#pragma unroll
      for (int reg = 0; reg < 4; reg++) {
        unsigned mine = f2bf(hc[reg]);
        unsigned other = (unsigned)__shfl_xor((int)mine, 1, 64);
        if ((lane & 1) == 0) {
          unsigned packed = mine | (other << 16);
          AS(&hout[(size_t)(bbase + reg) * (NN / 2) + (j >> 1)], packed);
        }
      }
      asm volatile("s_waitcnt vmcnt(0)" ::: "memory");  // h stores LLC-visible
      if (tid == 0) AS(&f[bid], (unsigned)(t + 1));
    }
    pz += pstride; pr += pstride; pv += pstride;
  }

  if (wave == 0) {   // out[b*N + j] straight from registers
#pragma unroll
    for (int reg = 0; reg < 4; reg++)
      out[(size_t)(bbase + reg) * NN + j] = hc[reg];
  }
}

extern "C" void kernel_launch(void* const* d_in, const int* in_sizes, int n_in,
                              void* d_out, int out_size, void* d_ws, size_t ws_size,
                              hipStream_t stream) {
  const float* flow_x = (const float*)d_in[0];
  const float* W1 = (const float*)d_in[1];
  const float* b1 = (const float*)d_in[2];
  const float* W2 = (const float*)d_in[3];
  const float* b2 = (const float*)d_in[4];
  float* out = (float*)d_out;
  char* ws = (char*)d_ws;
  size_t off = 0;
  auto take = [&](size_t bytes) -> char* {
    char* p = ws + off;
    off += (bytes + 255) & ~(size_t)255;
    return p;
  };
  unsigned short* wt  = (unsigned short*)take((size_t)3 * 1024 * 1024 * 2);
  unsigned short* xT  = (unsigned short*)take((size_t)32768 * 1024 * 2);
  unsigned short* P2  = (unsigned short*)take((size_t)512 * 3 * 1024 * 64 * 2);
  unsigned short* hb  = (unsigned short*)take((size_t)4 * HB_ELEMS * 2);
  unsigned*       f   = (unsigned*)take((size_t)256 * 4);
  unsigned*       cons= (unsigned*)take((size_t)256 * 4);

  if (off > ws_size) {
    hipMemsetAsync(d_out, 0, (size_t)out_size * 4, stream);
    return;
  }

  hipMemsetAsync(hb, 0, HB_ELEMS * 2, stream);        // slot 0: h_0 = 0
  hipMemsetAsync(f, 0, 256 * 4, stream);
  hipMemsetAsync(cons, 0, 256 * 4, stream);

  prep_w<<<768, 256, 0, stream>>>(W1, W2, wt);
  trans_x<<<8192, 256, 0, stream>>>(flow_x, xT);
  precompute<<<6144, 256, 0, stream>>>(xT, wt, b1, b2, P2);

  void* args[] = {&hb, &wt, &P2, &b1, &b2, &out, &f, &cons};
  hipLaunchCooperativeKernel((const void*)gru_scan, dim3(256), dim3(256),
                             args, 0, stream);
}

// Round 5
// 3567.449 us; speedup vs baseline: 1.5794x; 1.5794x over previous
//
#include <hip/hip_runtime.h>

// GRU, B=64, N=1024, T=512.
// Phase 1 (parallel): transpose x, weights -> bf16 [n][k], precompute
//   P2[t][s][j][b] = (x_t @ {W1z,W1r,W2} + bias) in bf16.
// Phase 2: ONE persistent kernel, 256 blocks x 256 thr = 4 INDEPENDENT
//   64-block scans (per 16-batch group mq). Sync: per-(group,K-quarter)
//   publish counters at LLC. Reader wave w polls ONE word (cnt[g][w] >= 16t,
//   all lanes same address, s_sleep backoff) -> depends on only 16 writers.
//   h ring: 4 slots; no consume flags needed (arrival implies retirement).
//   All cross-block h traffic via relaxed agent-scope (sc1/LLC) atomics.

#define BATCH 64
#define NN 1024
#define TSTEPS 512
#define HB_ELEMS ((size_t)BATCH * NN)          // 65536 shorts per ring slot

typedef __attribute__((ext_vector_type(8))) short short8;
typedef __attribute__((ext_vector_type(8))) unsigned short u16x8;
typedef __attribute__((ext_vector_type(4))) unsigned short u16x4;
typedef __attribute__((ext_vector_type(4))) float f32x4;

#define MFMA16(a, b, c) __builtin_amdgcn_mfma_f32_16x16x32_bf16((a), (b), (c), 0, 0, 0)

__device__ __forceinline__ unsigned short f2bf(float x) {
  union { float f; unsigned u; } v; v.f = x;
  unsigned u = v.u + 0x7FFFu + ((v.u >> 16) & 1u);   // round-to-nearest-even
  return (unsigned short)(u >> 16);
}
__device__ __forceinline__ float bf2f(unsigned short h) {
  union { unsigned u; float f; } v; v.u = ((unsigned)h) << 16; return v.f;
}

// ---- transpose flow_x [64][1024][512] fp32 -> xT [(t*64+b)][k] bf16 ----
__global__ void trans_x(const float* __restrict__ fx, unsigned short* __restrict__ xT) {
  int bid = blockIdx.x;
  int b   = bid >> 7;
  int rem = bid & 127;
  int kt  = rem >> 3;
  int tt  = rem & 7;
  __shared__ float tl[64][65];
  int tx = threadIdx.x & 63;
  int ty = threadIdx.x >> 6;
  const float* src = fx + ((size_t)(b * NN + kt * 64)) * TSTEPS + tt * 64;
#pragma unroll
  for (int i = 0; i < 16; i++) {
    int kr = i * 4 + ty;
    tl[kr][tx] = src[(size_t)kr * TSTEPS + tx];
  }
  __syncthreads();
#pragma unroll
  for (int i = 0; i < 16; i++) {
    int tr = i * 4 + ty;
    xT[((size_t)((tt * 64 + tr) * 64 + b)) * NN + kt * 64 + tx] = f2bf(tl[tx][tr]);
  }
}

// ---- weights fp32 -> wt bf16 [3*1024 rows n=(s,j)][1024 k] ----
__global__ void prep_w(const float* __restrict__ W1, const float* __restrict__ W2,
                       unsigned short* __restrict__ wt) {
  int bid = blockIdx.x;
  int s    = bid >> 8;
  int tile = bid & 255;
  int kt = tile >> 4, jt = tile & 15;
  const float* src = (s < 2) ? W1 : W2;
  int ld = (s < 2) ? 2048 : 1024;
  int co = (s == 1) ? 1024 : 0;
  __shared__ float tl[64][65];
  int tx = threadIdx.x & 63, ty = threadIdx.x >> 6;
#pragma unroll
  for (int i = 0; i < 16; i++) {
    int kr = i * 4 + ty;
    tl[kr][tx] = src[(size_t)(kt * 64 + kr) * ld + co + jt * 64 + tx];
  }
  __syncthreads();
#pragma unroll
  for (int i = 0; i < 16; i++) {
    int jr = i * 4 + ty;
    wt[((size_t)(s * NN + jt * 64 + jr)) * NN + kt * 64 + tx] = f2bf(tl[tx][jr]);
  }
}

// ---- P2[t][s][j][b] = x @ [W1 | W2] + bias, bf16 ----
__global__ __launch_bounds__(256) void precompute(
    const unsigned short* __restrict__ xT, const unsigned short* __restrict__ wt,
    const float* __restrict__ b1, const float* __restrict__ b2,
    unsigned short* __restrict__ P2) {
  int m0 = (blockIdx.x / 24) * 128;
  int n0 = (blockIdx.x % 24) * 128;
  __shared__ unsigned short As[128 * 40];
  __shared__ unsigned short Bs[128 * 40];
  int tid = threadIdx.x;
  int wave = tid >> 6, lane = tid & 63, q = lane >> 4, li = lane & 15;
  int wm = wave >> 1, wn = wave & 1;
  f32x4 acc[4][4];
#pragma unroll
  for (int a = 0; a < 4; a++)
#pragma unroll
    for (int b = 0; b < 4; b++) acc[a][b] = (f32x4)(0.f);

  for (int kk = 0; kk < 32; ++kk) {
    int K0 = kk * 32;
#pragma unroll
    for (int e = 0; e < 2; e++) {
      int c = tid * 2 + e;
      int row = c >> 2, part = c & 3;
      *(u16x8*)&As[row * 40 + part * 8] =
          *(const u16x8*)&xT[(size_t)(m0 + row) * NN + K0 + part * 8];
      *(u16x8*)&Bs[row * 40 + part * 8] =
          *(const u16x8*)&wt[(size_t)(n0 + row) * NN + K0 + part * 8];
    }
    __syncthreads();
    short8 af[4], bfr[4];
#pragma unroll
    for (int mt = 0; mt < 4; mt++)
      af[mt] = *(const short8*)&As[(wm * 64 + mt * 16 + li) * 40 + q * 8];
#pragma unroll
    for (int nt = 0; nt < 4; nt++)
      bfr[nt] = *(const short8*)&Bs[(wn * 64 + nt * 16 + li) * 40 + q * 8];
#pragma unroll
    for (int mt = 0; mt < 4; mt++)
#pragma unroll
      for (int nt = 0; nt < 4; nt++)
        acc[mt][nt] = MFMA16(af[mt], bfr[nt], acc[mt][nt]);
    __syncthreads();
  }
#pragma unroll
  for (int mt = 0; mt < 4; mt++) {
    int m = m0 + wm * 64 + mt * 16 + q * 4;
    int t = m >> 6, b = m & 63;
#pragma unroll
    for (int nt = 0; nt < 4; nt++) {
      int n = n0 + wn * 64 + nt * 16 + li;
      float bias = (n < 2048) ? b1[n] : b2[n - 2048];
      int s = n >> 10, j = n & 1023;
      f32x4 a = acc[mt][nt];
      u16x4 pk;
      pk.x = f2bf(a.x + bias); pk.y = f2bf(a.y + bias);
      pk.z = f2bf(a.z + bias); pk.w = f2bf(a.w + bias);
      *(u16x4*)&P2[(((size_t)t * 3 + s) * NN + j) * 64 + b] = pk;
    }
  }
}

#define AL(p)    __hip_atomic_load((p),  __ATOMIC_RELAXED, __HIP_MEMORY_SCOPE_AGENT)
#define AS(p, v) __hip_atomic_store((p), (v), __ATOMIC_RELAXED, __HIP_MEMORY_SCOPE_AGENT)

// ---- persistent scan, per-(group,quarter) publish counters ----
// cnt[(mq*4+w)*64]: number of h publishes by writers jt in [16w,16w+16) of
// group mq. Reader wave w at step t waits cnt >= 16*t (h_t visible).
// h ring: 4 slots of [64 b][1024 j] bf16; slot t&3 holds h_t.
__global__ __launch_bounds__(256, 1) void gru_scan(
    unsigned short* __restrict__ hb, const unsigned short* __restrict__ wt,
    const unsigned short* __restrict__ P2,
    const float* __restrict__ b1, const float* __restrict__ b2,
    float* __restrict__ out, unsigned* __restrict__ cnt) {
  int bid = blockIdx.x;
  int jt = bid & 63, mq = bid >> 6;
  int j0 = jt * 16, m0 = mq * 16;
  int tid = threadIdx.x, wave = tid >> 6, lane = tid & 63, q = lane >> 4, li = lane & 15;
  int kb = wave * 256;   // this wave's K-quarter

  const short8* Bz = (const short8*)&wt[((size_t)(0 * NN + j0 + li)) * NN + kb + q * 8];
  const short8* Br = (const short8*)&wt[((size_t)(1 * NN + j0 + li)) * NN + kb + q * 8];
  const short8* Bv = (const short8*)&wt[((size_t)(2 * NN + j0 + li)) * NN + kb + q * 8];
  short8 wz[8], wr[8], wv[8];
#pragma unroll
  for (int r = 0; r < 8; r++) {
    wz[r] = Bz[r * 4];
    wr[r] = Br[r * 4];
    wv[r] = Bv[r * 4];
  }

  int j = j0 + li;
  int bbase = m0 + q * 4;
  float b1z = b1[j], b1r = b1[NN + j], b2v = b2[j];
  const unsigned short* pz = &P2[((size_t)0 * NN + j) * 64 + bbase];
  const unsigned short* pr = &P2[((size_t)1 * NN + j) * 64 + bbase];
  const unsigned short* pv = &P2[((size_t)2 * NN + j) * 64 + bbase];
  const size_t pstride = (size_t)3 * NN * 64;

  // this wave's poll word; this block's arrival counter
  unsigned* poll_w = &cnt[(mq * 4 + wave) * 64];
  unsigned* arr_w  = &cnt[(mq * 4 + (jt >> 4)) * 64];

  // A-fragment offset in u64 units within a ring slot
  const size_t aoff = (size_t)(m0 + li) * 256 + wave * 64 + q * 2;

  f32x4 hc = (f32x4)(0.f);   // wave0: fp32 h tile, resident all 512 steps
  __shared__ f32x4 red[9][64];

  for (int t = 0; t < TSTEPS; t++) {
    u16x4 pz4, pr4, pv4;
    if (wave == 0) {   // HBM P2 stream — independent of flags, issue first
      pz4 = *(const u16x4*)pz;
      pr4 = *(const u16x4*)pr;
      pv4 = *(const u16x4*)pv;
    }
    // wait for this quarter's 16 writers to have published h_t
    if (t > 0) {
      unsigned target = 16u * (unsigned)t;
      while (AL(poll_w) < target) __builtin_amdgcn_s_sleep(1);
    }
    // coherent A-loads from ring slot t&3 (16x dwordx2 per lane)
    const unsigned long long* hin =
        (const unsigned long long*)(hb + ((size_t)(t & 3)) * HB_ELEMS);
    union { unsigned long long u[2]; short8 s; } fa[8];
#pragma unroll
    for (int r = 0; r < 8; r++) {
      fa[r].u[0] = AL(hin + aoff + r * 8);
      fa[r].u[1] = AL(hin + aoff + r * 8 + 1);
    }
    f32x4 az = (f32x4)(0.f), ar = (f32x4)(0.f), av = (f32x4)(0.f);
#pragma unroll
    for (int r = 0; r < 8; r++) {
      az = MFMA16(fa[r].s, wz[r], az);
      ar = MFMA16(fa[r].s, wr[r], ar);
      av = MFMA16(fa[r].s, wv[r], av);
    }
    if (wave > 0) {
      red[(wave - 1) * 3 + 0][lane] = az;
      red[(wave - 1) * 3 + 1][lane] = ar;
      red[(wave - 1) * 3 + 2][lane] = av;
    }
    __syncthreads();   // all 4 quarters ready + partials in LDS
    if (wave == 0) {
#pragma unroll
      for (int w = 0; w < 3; w++) {
        az += red[w * 3 + 0][lane];
        ar += red[w * 3 + 1][lane];
        av += red[w * 3 + 2][lane];
      }
#pragma unroll
      for (int reg = 0; reg < 4; reg++) {
        float z = 1.f / (1.f + __expf(-(az[reg] + bf2f(pz4[reg]) + b1z)));
        float r = 1.f / (1.f + __expf(-(ar[reg] + bf2f(pr4[reg]) + b1r)));
        float x = bf2f(pv4[reg]) + r * (av[reg] + b2v);
        float e = __expf(-2.f * fabsf(x));        // overflow-safe tanh
        float th = (1.f - e) / (1.f + e);
        float hh = (x >= 0.f) ? th : -th;
        hc[reg] = z * hc[reg] + (1.f - z) * hh;
      }
      if (t < TSTEPS - 1) {
        // publish h_{t+1} into slot (t+1)&3 (hb[b][j], adjacent-j pairs).
        // Ring-reuse safe: reaching here implies cnt>=16t for all quarters
        // => every block finished step t-1 => step t-3 reads retired.
        unsigned* hout = (unsigned*)(hb + ((size_t)((t + 1) & 3)) * HB_ELEMS);
#pragma unroll
        for (int reg = 0; reg < 4; reg++) {
          unsigned mine = f2bf(hc[reg]);
          unsigned other = (unsigned)__shfl_xor((int)mine, 1, 64);
          if ((lane & 1) == 0) {
            unsigned packed = mine | (other << 16);
            AS(&hout[(size_t)(bbase + reg) * (NN / 2) + (j >> 1)], packed);
          }
        }
        asm volatile("s_waitcnt vmcnt(0)" ::: "memory");  // stores LLC-visible
        if (lane == 0)
          __hip_atomic_fetch_add(arr_w, 1u, __ATOMIC_RELAXED,
                                 __HIP_MEMORY_SCOPE_AGENT);
      }
    }
    pz += pstride; pr += pstride; pv += pstride;
  }

  if (wave == 0) {   // out[b*N + j] straight from registers
#pragma unroll
    for (int reg = 0; reg < 4; reg++)
      out[(size_t)(bbase + reg) * NN + j] = hc[reg];
  }
}

extern "C" void kernel_launch(void* const* d_in, const int* in_sizes, int n_in,
                              void* d_out, int out_size, void* d_ws, size_t ws_size,
                              hipStream_t stream) {
  const float* flow_x = (const float*)d_in[0];
  const float* W1 = (const float*)d_in[1];
  const float* b1 = (const float*)d_in[2];
  const float* W2 = (const float*)d_in[3];
  const float* b2 = (const float*)d_in[4];
  float* out = (float*)d_out;
  char* ws = (char*)d_ws;
  size_t off = 0;
  auto take = [&](size_t bytes) -> char* {
    char* p = ws + off;
    off += (bytes + 255) & ~(size_t)255;
    return p;
  };
  unsigned short* wt  = (unsigned short*)take((size_t)3 * 1024 * 1024 * 2);
  unsigned short* xT  = (unsigned short*)take((size_t)32768 * 1024 * 2);
  unsigned short* P2  = (unsigned short*)take((size_t)512 * 3 * 1024 * 64 * 2);
  unsigned short* hb  = (unsigned short*)take((size_t)4 * HB_ELEMS * 2);
  unsigned*       cnt = (unsigned*)take((size_t)16 * 64 * 4);

  if (off > ws_size) {
    hipMemsetAsync(d_out, 0, (size_t)out_size * 4, stream);
    return;
  }

  hipMemsetAsync(hb, 0, HB_ELEMS * 2, stream);        // slot 0: h_0 = 0
  hipMemsetAsync(cnt, 0, (size_t)16 * 64 * 4, stream);

  prep_w<<<768, 256, 0, stream>>>(W1, W2, wt);
  trans_x<<<8192, 256, 0, stream>>>(flow_x, xT);
  precompute<<<6144, 256, 0, stream>>>(xT, wt, b1, b2, P2);

  void* args[] = {&hb, &wt, &P2, &b1, &b2, &out, &cnt};
  hipLaunchCooperativeKernel((const void*)gru_scan, dim3(256), dim3(256),
                             args, 0, stream);
}